// Round 3
// baseline (127.104 us; speedup 1.0000x reference)
//
#include <hip/hip_runtime.h>

// x shape (8,32,256,256) float32 holding exact integers 0..255; K=3, stride 1, no pad.
#define B_   8
#define C_   32
#define H_   256
#define W_   256
#define BC_  (B_ * C_)
#define HO_  (H_ - 2)           // 254
#define WO_  (W_ - 2)           // 254
#define NIN_  (BC_ * H_ * W_)   // 16,777,216
#define NBINS 256
#define HCOLS 16                // sub-histogram columns (LDS-atomic aliasing ~2-way = free)
#define HBLOCKS 1024            // NIN_/4 = HBLOCKS*256*16 exactly

// v7: pool argmin made separable. Row-major argmin over 3x3 is lexicographic in
// (di,dj), so it = vertical-first-min over horizontal leftmost-first row-mins; the
// row-min of an input row is identical in all 3 windows using that row, so compute
// once per new row and carry 2 (key,mask) register pairs vertically. Per output:
// 4 CAND chains instead of 8 (~20 VALU vs ~37) — pool was marginally VALU-bound
// (~9.4 us VALU vs 10.5 us NT-write floor at 6.3 TB/s).
__device__ int g_hist8[8 * NBINS];        // 8 partial final histograms (reduce output)
__device__ int g_part[HBLOCKS * NBINS];   // 1 MB, fully overwritten each call

__global__ __launch_bounds__(256) void hist_kernel(const float* __restrict__ x) {
    __shared__ int sh[NBINS * HCOLS];   // 16 KB
    const int t = threadIdx.x;
    for (int i = t; i < NBINS * HCOLS; i += 256) sh[i] = 0;
    __syncthreads();

    const int col = t & (HCOLS - 1);
    const float4* x4 = (const float4*)x;
    const int stride = HBLOCKS * 256;          // 262144 float4s
    float4 v[8];
#pragma unroll
    for (int half = 0; half < 2; ++half) {
        const int base = blockIdx.x * 256 + t + half * 8 * stride;
#pragma unroll
        for (int k = 0; k < 8; ++k) v[k] = x4[base + k * stride];  // 8 loads in flight
#pragma unroll
        for (int k = 0; k < 8; ++k) {
            atomicAdd(&sh[((int)v[k].x) * HCOLS + col], 1);
            atomicAdd(&sh[((int)v[k].y) * HCOLS + col], 1);
            atomicAdd(&sh[((int)v[k].z) * HCOLS + col], 1);
            atomicAdd(&sh[((int)v[k].w) * HCOLS + col], 1);
        }
    }
    __syncthreads();

    // Per-bin column sum, rotated so bank = (17t+c) mod 32 (2-way = free); plain store.
    int s0 = 0;
#pragma unroll
    for (int c = 0; c < HCOLS; ++c) {
        const int cc = (c + t) & (HCOLS - 1);
        s0 += sh[t * HCOLS + cc];
    }
    g_part[blockIdx.x * NBINS + t] = s0;
}

// 8 blocks x 256 threads: block j sums partial rows [j*128, j*128+128) (coalesced,
// unroll-8 MLP), then ONE plain store per thread into its own g_hist8 row.
__global__ __launch_bounds__(256) void reduce_kernel() {
    const int t = threadIdx.x;
    const int r0 = blockIdx.x * (HBLOCKS / 8);
    int s = 0;
#pragma unroll 8
    for (int i = 0; i < HBLOCKS / 8; ++i) s += g_part[(r0 + i) * NBINS + t];
    g_hist8[blockIdx.x * NBINS + t] = s;
}

// Block = one (bc, 16-output-row strip). Sum the 8 partial histograms (L2-hot
// broadcast), build key table (key = (count<<8)|value), load 18x256 f32 input tile
// (L3-hot — hist just read x), translate once per input element to keys in LDS.
// Compute: per output, ONE new horizontal row-min (leftmost-on-tie, strict '<')
// + vertical first-min over 3 carried row-mins (topmost-on-tie) == exact row-major
// positional first-min (matches jnp.argmin). Output stored non-temporally.
__global__ __launch_bounds__(256) void pool_kernel(const float* __restrict__ x,
                                                   float* __restrict__ out) {
    __shared__ int key_s[NBINS];
    __shared__ int tile[18 * W_];   // 18 KB
    const int t = threadIdx.x;
    int h = 0;
#pragma unroll
    for (int j = 0; j < 8; ++j) h += g_hist8[j * NBINS + t];
    key_s[t] = (h << 8) | t;
    __syncthreads();

    const int bc = blockIdx.x >> 4;
    const int s  = blockIdx.x & 15;
    const int r0 = s * 16;
    const int rows_out = (r0 + 16 <= HO_) ? 16 : (HO_ - r0);  // 16, last strip 14
    const int rows_in  = rows_out + 2;                        // 18 / 16 (fits H_)

    const float4* xin = (const float4*)(x + ((long long)bc * H_ + r0) * W_);
    const int nf4 = rows_in * (W_ / 4);
    for (int idx = t; idx < nf4; idx += 256) {
        float4 v = xin[idx];
        int4 k;
        k.x = key_s[(int)v.x];
        k.y = key_s[(int)v.y];
        k.z = key_s[(int)v.z];
        k.w = key_s[(int)v.w];
        ((int4*)tile)[idx] = k;
    }
    __syncthreads();

    if (t >= WO_) return;   // no further barriers below

    // Horizontal leftmost-first-min of a row triple -> (key RK, masked count RM).
#define HMIN(ROWBASE, RK, RM) {                                                  \
        const int e0_ = tile[(ROWBASE) + t];                                     \
        const int e1_ = tile[(ROWBASE) + t + 1];                                 \
        const int e2_ = tile[(ROWBASE) + t + 2];                                 \
        RK = e0_; RM = e0_ & ~255;                                               \
        const int m1_ = e1_ & ~255; if (m1_ < RM) { RM = m1_; RK = e1_; }        \
        const int m2_ = e2_ & ~255; if (m2_ < RM) { RM = m2_; RK = e2_; } }

    int ak, am, bk, bm;
    HMIN(0,  ak, am)
    HMIN(W_, bk, bm)
    float* orow = out + ((long long)bc * HO_ + r0) * WO_ + t;
#pragma unroll 4
    for (int r = 0; r < rows_out; ++r) {
        int ck, cm;
        HMIN((r + 2) * W_, ck, cm)
        int wk = ak, wm = am;                    // di=0 wins ties
        if (bm < wm) { wm = bm; wk = bk; }       // di=1 strictly smaller only
        if (cm < wm) { wm = cm; wk = ck; }       // di=2 strictly smaller only
        __builtin_nontemporal_store((float)(wk & 255), &orow[(long long)r * WO_]);
        ak = bk; am = bm;
        bk = ck; bm = cm;
    }
#undef HMIN
}

extern "C" void kernel_launch(void* const* d_in, const int* in_sizes, int n_in,
                              void* d_out, int out_size, void* d_ws, size_t ws_size,
                              hipStream_t stream) {
    const float* x = (const float*)d_in[0];
    float* out = (float*)d_out;
    (void)d_ws; (void)ws_size;

    hist_kernel<<<HBLOCKS, 256, 0, stream>>>(x);
    reduce_kernel<<<8, 256, 0, stream>>>();
    pool_kernel<<<BC_ * 16, 256, 0, stream>>>(x, out);
}